// Round 3
// baseline (1776.075 us; speedup 1.0000x reference)
//
#include <hip/hip_runtime.h>
#include <math.h>

#define DD 128

typedef __attribute__((ext_vector_type(8))) short short8;   // 8 x bf16 bits
typedef __attribute__((ext_vector_type(4))) float f32x4;

__device__ inline short bf16hi(float x) {
  unsigned u = __float_as_uint(x);
  unsigned r = u + 0x7fffu + ((u >> 16) & 1u);  // RTNE
  return (short)(r >> 16);
}
__device__ inline float bf16tof(short h) {
  return __uint_as_float(((unsigned)(unsigned short)h) << 16);
}
__device__ inline void split2(float x, short& hi, short& lo) {  // RTNE (node kernel)
  hi = bf16hi(x);
  float rem = x - bf16tof(hi);
  lo = bf16hi(rem);
}
__device__ inline void splitT(float x, short& hi, short& lo) {  // truncation (cheap)
  unsigned u = __float_as_uint(x);
  hi = (short)(u >> 16);
  float rem = x - __uint_as_float(u & 0xffff0000u);
  lo = (short)(__float_as_uint(rem) >> 16);
}

// ---------------- small helper kernels ----------------
__global__ __launch_bounds__(128) void zero128_kernel(float* p) { p[threadIdx.x] = 0.f; }

__global__ __launch_bounds__(256) void colsum_kernel(const float* __restrict__ x,
                                                     float* __restrict__ colsum, int N) {
  int col = threadIdx.x & 127;
  int part = (blockIdx.x * blockDim.x + threadIdx.x) >> 7;
  int nparts = (gridDim.x * blockDim.x) >> 7;
  float s = 0.f;
  for (int r = part; r < N; r += nparts) s += x[(size_t)r * DD + col];
  atomicAdd(&colsum[col], s);
}

__global__ __launch_bounds__(128) void glb_kernel(const float* __restrict__ colsum,
                                                  const float* __restrict__ glb_W,
                                                  const float* __restrict__ glb_b,
                                                  float* __restrict__ g, float invN) {
  __shared__ float m[DD];
  int j = threadIdx.x;
  m[j] = colsum[j] * invN;
  __syncthreads();
  float s = glb_b[j];
#pragma unroll 8
  for (int k = 0; k < DD; ++k) s = fmaf(m[k], glb_W[k * DD + j], s);
  g[j] = fmaxf(s, 0.f);
}

// Weight prep:
//  W1F: fragment-major for edge GEMM1. Frag id = (c in [0,8) k32-chunk, n in [0,16) ntile,
//       p in {hi,lo}, lane in [0,64)): element j: col=n*16+(lane&15), k=c*32+(lane>>4)*8+j.
//       Linear: W1F[(((c*16+n)*2+p)*64+lane)*8 + j].  32KB per chunk slice.
//  W2F: same for GEMM2 (4 chunks, 8 ntiles).
//  U1T/U2T: col-major hi/lo planes for the node kernel (unchanged layout).
__global__ __launch_bounds__(256) void conv_kernel(
    const float* __restrict__ msg_W1, const float* __restrict__ att_W1,
    const float* __restrict__ msg_W2, const float* __restrict__ upd_W1,
    const float* __restrict__ upd_W2,
    short* __restrict__ W1F, short* __restrict__ W2F,
    short* __restrict__ U1hiT, short* __restrict__ U1loT,
    short* __restrict__ U2hiT, short* __restrict__ U2loT) {
  int i = blockIdx.x * 256 + threadIdx.x;  // 0 .. 69631
  if (i < 16384) {
    int lane = i & 63, p = (i >> 6) & 1, n = (i >> 7) & 15, c = i >> 11;
    int col = n * 16 + (lane & 15);
#pragma unroll
    for (int j = 0; j < 8; ++j) {
      int k = c * 32 + (lane >> 4) * 8 + j;
      float v = (col < 128) ? msg_W1[k * 128 + col] : att_W1[k * 128 + (col - 128)];
      short hi, lo; splitT(v, hi, lo);
      W1F[(size_t)i * 8 + j] = p ? lo : hi;
    }
  } else if (i < 20480) {
    int gI = i - 16384;
    int lane = gI & 63, p = (gI >> 6) & 1, n = (gI >> 7) & 7, c = gI >> 10;
    int col = n * 16 + (lane & 15);
#pragma unroll
    for (int j = 0; j < 8; ++j) {
      int k = c * 32 + (lane >> 4) * 8 + j;
      float v = msg_W2[k * 128 + col];
      short hi, lo; splitT(v, hi, lo);
      W2F[(size_t)gI * 8 + j] = p ? lo : hi;
    }
  } else if (i < 53248) {
    int j = i - 20480;  // 32768 elems: col 0..127, k 0..255
    int col = j & 127, k = j >> 7;
    float v = upd_W1[k * 128 + col];
    short hi, lo; split2(v, hi, lo);
    U1hiT[col * 256 + k] = hi; U1loT[col * 256 + k] = lo;
  } else if (i < 69632) {
    int j = i - 53248;
    int col = j & 127, k = (j >> 7) & 127;
    float v = upd_W2[k * 128 + col];
    short hi, lo; split2(v, hi, lo);
    U2hiT[col * 128 + k] = hi; U2loT[col * 128 + k] = lo;
  }
}

// ---------------- fused edge kernel v3 ----------------
// Block: 256 thr = 4 waves; 96 edges/block (6 Mtiles of 16, all rows per wave).
// GEMM1: [96x256] @ W1[256x256]; waves column-split (wave wn: ntiles 4wn..4wn+3).
// A from global (registers, trunc-split); B staged to LDS (frag-major, reg-prefetch).
// Then: waves 0,1 -> msg hidden packed u32 to LDS; waves 2,3 -> att dot (shuffle).
// GEMM2: [96x128] @ W2 (B frags from global); sigmoid-weighted atomic scatter.
__global__ __launch_bounds__(256, 2) void edge_mfma_kernel(
    const float* __restrict__ h, const int* __restrict__ src, const int* __restrict__ dst,
    const short* __restrict__ W1F, const short* __restrict__ W2F,
    const float* __restrict__ msg_b1, const float* __restrict__ att_b1,
    const float* __restrict__ msg_b2, const float* __restrict__ att_W2,
    const float* __restrict__ att_b2, float* __restrict__ agg, int E) {
  __shared__ __align__(16) char smem[52608];
  short* Bb = (short*)smem;                 // [0,32768): B chunk, frag-major
  unsigned* HID = (unsigned*)smem;          // [0,50688): 96 x 132 packed u32 (overlays Bb)
  float* attP = (float*)(smem + 50688);     // 2 x 96
  float* attL = (float*)(smem + 51456);     // 96
  int* srcL = (int*)(smem + 51840);         // 96
  int* dstL = (int*)(smem + 52224);         // 96

  const int tid = threadIdx.x;
  const int wn = tid >> 6;
  const int lane = tid & 63;
  const int m16 = lane & 15, q = lane >> 4;
  const int e0 = blockIdx.x * 96;

  if (tid < 96) {
    int e = min(e0 + tid, E - 1);
    srcL[tid] = src[e];
    dstL[tid] = dst[e];
  }
  const float ab2 = att_b2[0];
  __syncthreads();

  int srcN[6], dstN[6];
#pragma unroll
  for (int mt = 0; mt < 6; ++mt) {
    int row = mt * 16 + m16;
    srcN[mt] = srcL[row];
    dstN[mt] = dstL[row];
  }

  // ---- GEMM1 ----
  f32x4 acc[6][4];
#pragma unroll
  for (int ntl = 0; ntl < 4; ++ntl) {
    int cg = wn * 64 + ntl * 16 + m16;
    float b = (cg < 128) ? msg_b1[cg] : att_b1[cg - 128];
#pragma unroll
    for (int mt = 0; mt < 6; ++mt) acc[mt][ntl] = (f32x4){b, b, b, b};
  }

  uint4 stg[8];
  {
    const uint4* gsrc = (const uint4*)W1F;
#pragma unroll
    for (int r = 0; r < 8; ++r) stg[r] = gsrc[tid + 256 * r];
  }

  for (int c = 0; c < 8; ++c) {
    __syncthreads();
#pragma unroll
    for (int r = 0; r < 8; ++r) ((uint4*)Bb)[tid + 256 * r] = stg[r];
    __syncthreads();
    if (c < 7) {
      const uint4* gsrc = (const uint4*)(W1F + (size_t)(c + 1) * 16384);
#pragma unroll
      for (int r = 0; r < 8; ++r) stg[r] = gsrc[tid + 256 * r];
    }
    // A fragments for this chunk (EF k in [32c, 32c+32))
    const int kb = (c & 3) * 32 + q * 8;
    short8 ah[6], al[6];
#pragma unroll
    for (int mt = 0; mt < 6; ++mt) {
      const float* p = h + (size_t)(c < 4 ? srcN[mt] : dstN[mt]) * DD + kb;
      float4 v0 = *(const float4*)p;
      float4 v1 = *(const float4*)(p + 4);
      float f[8] = {v0.x, v0.y, v0.z, v0.w, v1.x, v1.y, v1.z, v1.w};
#pragma unroll
      for (int j = 0; j < 8; ++j) { short hi, lo; splitT(f[j], hi, lo); ah[mt][j] = hi; al[mt][j] = lo; }
    }
#pragma unroll
    for (int ntl = 0; ntl < 4; ++ntl) {
      int nt = wn * 4 + ntl;
      short8 bh = *(const short8*)(Bb + ((size_t)(nt * 2 + 0) * 64 + lane) * 8);
      short8 bl = *(const short8*)(Bb + ((size_t)(nt * 2 + 1) * 64 + lane) * 8);
#pragma unroll
      for (int mt = 0; mt < 6; ++mt) {
        acc[mt][ntl] = __builtin_amdgcn_mfma_f32_16x16x32_bf16(ah[mt], bh, acc[mt][ntl], 0, 0, 0);
        acc[mt][ntl] = __builtin_amdgcn_mfma_f32_16x16x32_bf16(al[mt], bh, acc[mt][ntl], 0, 0, 0);
        acc[mt][ntl] = __builtin_amdgcn_mfma_f32_16x16x32_bf16(ah[mt], bl, acc[mt][ntl], 0, 0, 0);
      }
    }
  }
  __syncthreads();  // all Bb reads done before HID overlays

  if (wn < 2) {
    // msg hidden -> LDS, relu + trunc-split packed (hi<<16 | lo)
#pragma unroll
    for (int mt = 0; mt < 6; ++mt)
#pragma unroll
      for (int ntl = 0; ntl < 4; ++ntl) {
        int col = wn * 64 + ntl * 16 + m16;
#pragma unroll
        for (int r = 0; r < 4; ++r) {
          int row = mt * 16 + q * 4 + r;
          float v = fmaxf(acc[mt][ntl][r], 0.f);
          short hi, lo; splitT(v, hi, lo);
          HID[row * 132 + col] =
              (((unsigned)(unsigned short)hi) << 16) | (unsigned)(unsigned short)lo;
        }
      }
  } else {
    // attention: dot(relu(att_hid), att_W2), reduce over 16 col-lanes
    float aw[4];
#pragma unroll
    for (int ntl = 0; ntl < 4; ++ntl) aw[ntl] = att_W2[(wn - 2) * 64 + ntl * 16 + m16];
    float p[6][4];
#pragma unroll
    for (int mt = 0; mt < 6; ++mt)
#pragma unroll
      for (int r = 0; r < 4; ++r) p[mt][r] = 0.f;
#pragma unroll
    for (int mt = 0; mt < 6; ++mt)
#pragma unroll
      for (int ntl = 0; ntl < 4; ++ntl)
#pragma unroll
        for (int r = 0; r < 4; ++r)
          p[mt][r] = fmaf(fmaxf(acc[mt][ntl][r], 0.f), aw[ntl], p[mt][r]);
#pragma unroll
    for (int mask = 1; mask < 16; mask <<= 1)
#pragma unroll
      for (int mt = 0; mt < 6; ++mt)
#pragma unroll
        for (int r = 0; r < 4; ++r) p[mt][r] += __shfl_xor(p[mt][r], mask);
    if (m16 == 0) {
#pragma unroll
      for (int mt = 0; mt < 6; ++mt)
#pragma unroll
        for (int r = 0; r < 4; ++r)
          attP[(wn - 2) * 96 + mt * 16 + q * 4 + r] = p[mt][r];
    }
  }
  __syncthreads();
  if (tid < 96) attL[tid] = 1.f / (1.f + expf(-(attP[tid] + attP[96 + tid] + ab2)));
  __syncthreads();

  // ---- GEMM2: [96x128] = hid @ W2 ; wave grid 2(M) x 2(N) ----
  const int wm2 = wn >> 1, wn2 = wn & 1;
  f32x4 acc2[3][4];
#pragma unroll
  for (int ntl = 0; ntl < 4; ++ntl) {
    float b = msg_b2[wn2 * 64 + ntl * 16 + m16];
#pragma unroll
    for (int mt = 0; mt < 3; ++mt) acc2[mt][ntl] = (f32x4){b, b, b, b};
  }
  for (int c2 = 0; c2 < 4; ++c2) {
    short8 a2h[3], a2l[3];
#pragma unroll
    for (int mt = 0; mt < 3; ++mt) {
      int row = wm2 * 48 + mt * 16 + m16;
      const unsigned* hp = &HID[row * 132 + c2 * 32 + q * 8];
      uint4 u0 = *(const uint4*)hp;
      uint4 u1 = *(const uint4*)(hp + 4);
      unsigned u[8] = {u0.x, u0.y, u0.z, u0.w, u1.x, u1.y, u1.z, u1.w};
#pragma unroll
      for (int j = 0; j < 8; ++j) {
        a2h[mt][j] = (short)(u[j] >> 16);
        a2l[mt][j] = (short)(u[j] & 0xffffu);
      }
    }
#pragma unroll
    for (int ntl = 0; ntl < 4; ++ntl) {
      int nt = wn2 * 4 + ntl;
      const short* bp = W2F + ((size_t)((c2 * 8 + nt) * 2 + 0) * 64 + lane) * 8;
      short8 bh = *(const short8*)bp;
      short8 bl = *(const short8*)(W2F + ((size_t)((c2 * 8 + nt) * 2 + 1) * 64 + lane) * 8);
#pragma unroll
      for (int mt = 0; mt < 3; ++mt) {
        acc2[mt][ntl] = __builtin_amdgcn_mfma_f32_16x16x32_bf16(a2h[mt], bh, acc2[mt][ntl], 0, 0, 0);
        acc2[mt][ntl] = __builtin_amdgcn_mfma_f32_16x16x32_bf16(a2l[mt], bh, acc2[mt][ntl], 0, 0, 0);
        acc2[mt][ntl] = __builtin_amdgcn_mfma_f32_16x16x32_bf16(a2h[mt], bl, acc2[mt][ntl], 0, 0, 0);
      }
    }
  }

  // ---- weighted atomic scatter ----
#pragma unroll
  for (int mt = 0; mt < 3; ++mt)
#pragma unroll
    for (int r = 0; r < 4; ++r) {
      int row = wm2 * 48 + mt * 16 + q * 4 + r;
      if (e0 + row < E) {
        float av = attL[row];
        float* base = agg + (size_t)dstL[row] * DD;
#pragma unroll
        for (int ntl = 0; ntl < 4; ++ntl) {
          int col = wn2 * 64 + ntl * 16 + m16;
          atomicAdd(base + col, acc2[mt][ntl][r] * av);
        }
      }
    }
}

// ---------------- node update kernel (unchanged, verified) ----------------
__global__ __launch_bounds__(256, 2) void node_mfma_kernel(
    const float* __restrict__ h, const float* __restrict__ agg,
    const short* __restrict__ U1hiT, const short* __restrict__ U1loT,
    const short* __restrict__ U2hiT, const short* __restrict__ U2loT,
    const float* __restrict__ upd_b1, const float* __restrict__ upd_b2,
    const float* __restrict__ g, float* __restrict__ out, int N) {
  __shared__ short smem[29184];
  short* WT1hi = smem;            // 128 cols x 40
  short* WT1lo = smem + 5120;
  short* HIDlo = smem + 10240;
  short* HIDhi = smem + 20480;

  const int tid = threadIdx.x;
  const int wave = tid >> 6;
  const int lane = tid & 63;
  const int m16 = lane & 15;
  const int q = lane >> 4;

  const int n0 = blockIdx.x * 64;
  const int nA = n0 + wave * 16 + m16;
  const int nAc = min(nA, N - 1);

  short8 a1h[8], a1l[8];
  {
    const float* rs = h + (size_t)nAc * DD;
    const float* rd = agg + (size_t)nAc * DD;
#pragma unroll
    for (int t = 0; t < 8; ++t) {
      const float* base = ((t < 4) ? (rs + t * 32) : (rd + (t - 4) * 32)) + q * 8;
      float4 v0 = *(const float4*)(base);
      float4 v1 = *(const float4*)(base + 4);
      float f[8] = {v0.x, v0.y, v0.z, v0.w, v1.x, v1.y, v1.z, v1.w};
      short8 hh, ll;
#pragma unroll
      for (int j = 0; j < 8; ++j) { short hi, lo; split2(f[j], hi, lo); hh[j] = hi; ll[j] = lo; }
      a1h[t] = hh; a1l[t] = ll;
    }
  }

  f32x4 acc[8];
#pragma unroll
  for (int n = 0; n < 8; ++n) {
    float b = upd_b1[n * 16 + m16];
    acc[n] = (f32x4){b, b, b, b};
  }

  for (int t = 0; t < 8; ++t) {
    __syncthreads();
#pragma unroll
    for (int r = 0; r < 4; ++r) {
      int idx = tid + 256 * r;
      int comp = idx >> 9;
      int cid = idx & 511;
      int col = cid >> 2, sub = cid & 3;
      const short* gsrc = (comp ? U1loT : U1hiT) + col * 256 + t * 32 + sub * 8;
      short* ldst = (comp ? WT1lo : WT1hi) + col * 40 + sub * 8;
      *(short8*)ldst = *(const short8*)gsrc;
    }
    __syncthreads();
#pragma unroll
    for (int n = 0; n < 8; ++n) {
      const short* bp = WT1hi + (n * 16 + m16) * 40 + q * 8;
      short8 bh = *(const short8*)bp;
      short8 bl = *(const short8*)(bp + 5120);
      acc[n] = __builtin_amdgcn_mfma_f32_16x16x32_bf16(a1h[t], bh, acc[n], 0, 0, 0);
      acc[n] = __builtin_amdgcn_mfma_f32_16x16x32_bf16(a1l[t], bh, acc[n], 0, 0, 0);
      acc[n] = __builtin_amdgcn_mfma_f32_16x16x32_bf16(a1h[t], bl, acc[n], 0, 0, 0);
    }
  }

  __syncthreads();
#pragma unroll
  for (int n = 0; n < 8; ++n) {
    int col = n * 16 + m16;
#pragma unroll
    for (int r = 0; r < 4; ++r) {
      int row = wave * 16 + q * 4 + r;
      float v = fmaxf(acc[n][r], 0.f);
      short hi, lo; split2(v, hi, lo);
      HIDhi[row * 136 + col] = hi;
      HIDlo[row * 136 + col] = lo;
    }
  }
  __syncthreads();

  short8 a2h[4], a2l[4];
  {
    int mrow = wave * 16 + m16;
#pragma unroll
    for (int t = 0; t < 4; ++t) {
      a2h[t] = *(const short8*)(HIDhi + mrow * 136 + t * 32 + q * 8);
      a2l[t] = *(const short8*)(HIDlo + mrow * 136 + t * 32 + q * 8);
    }
  }

  f32x4 acc2[8];
#pragma unroll
  for (int n = 0; n < 8; ++n) {
    float b = upd_b2[n * 16 + m16];
    acc2[n] = (f32x4){b, b, b, b};
  }

  for (int t = 0; t < 4; ++t) {
    __syncthreads();
#pragma unroll
    for (int r = 0; r < 4; ++r) {
      int idx = tid + 256 * r;
      int comp = idx >> 9;
      int cid = idx & 511;
      int col = cid >> 2, sub = cid & 3;
      const short* gsrc = (comp ? U2loT : U2hiT) + col * 128 + t * 32 + sub * 8;
      short* ldst = (comp ? WT1lo : WT1hi) + col * 40 + sub * 8;
      *(short8*)ldst = *(const short8*)gsrc;
    }
    __syncthreads();
#pragma unroll
    for (int n = 0; n < 8; ++n) {
      const short* bp = WT1hi + (n * 16 + m16) * 40 + q * 8;
      short8 bh = *(const short8*)bp;
      short8 bl = *(const short8*)(bp + 5120);
      acc2[n] = __builtin_amdgcn_mfma_f32_16x16x32_bf16(a2h[t], bh, acc2[n], 0, 0, 0);
      acc2[n] = __builtin_amdgcn_mfma_f32_16x16x32_bf16(a2l[t], bh, acc2[n], 0, 0, 0);
      acc2[n] = __builtin_amdgcn_mfma_f32_16x16x32_bf16(a2h[t], bl, acc2[n], 0, 0, 0);
    }
  }

#pragma unroll
  for (int r = 0; r < 4; ++r) {
    int rowN = n0 + wave * 16 + q * 4 + r;
    if (rowN < N) {
#pragma unroll
      for (int n = 0; n < 8; ++n) {
        int col = n * 16 + m16;
        out[(size_t)rowN * DD + col] = acc2[n][r] + h[(size_t)rowN * DD + col] + g[col];
      }
    }
  }
}

extern "C" void kernel_launch(void* const* d_in, const int* in_sizes, int n_in,
                              void* d_out, int out_size, void* d_ws, size_t ws_size,
                              hipStream_t stream) {
  const float* x = (const float*)d_in[0];
  const int* ei = (const int*)d_in[1];
  const float* msg_W1 = (const float*)d_in[2];
  const float* msg_b1 = (const float*)d_in[3];
  const float* msg_W2 = (const float*)d_in[4];
  const float* msg_b2 = (const float*)d_in[5];
  const float* upd_W1 = (const float*)d_in[6];
  const float* upd_b1 = (const float*)d_in[7];
  const float* upd_W2 = (const float*)d_in[8];
  const float* upd_b2 = (const float*)d_in[9];
  const float* att_W1 = (const float*)d_in[10];
  const float* att_b1 = (const float*)d_in[11];
  const float* att_W2 = (const float*)d_in[12];
  const float* att_b2 = (const float*)d_in[13];
  const float* glb_W = (const float*)d_in[14];
  const float* glb_b = (const float*)d_in[15];

  const int N = in_sizes[0] / DD;
  const int E = in_sizes[1] / 2;
  const int* src = ei;
  const int* dst = ei + E;

  float* out = (float*)d_out;
  float* agg = (float*)d_ws;                 // N*128 f32
  float* colsum = agg + (size_t)N * DD;      // 128
  float* g = colsum + DD;                    // 128
  short* U1hiT = (short*)(g + DD);
  short* U1loT = U1hiT + 32768;
  short* U2hiT = U1loT + 32768;
  short* U2loT = U2hiT + 16384;
  short* W1F = U2loT + 16384;                // 131072 shorts
  short* W2F = W1F + 131072;                 // 32768 shorts

  conv_kernel<<<272, 256, 0, stream>>>(msg_W1, att_W1, msg_W2, upd_W1, upd_W2,
                                       W1F, W2F, U1hiT, U1loT, U2hiT, U2loT);
  zero128_kernel<<<1, 128, 0, stream>>>(colsum);
  colsum_kernel<<<256, 256, 0, stream>>>(x, colsum, N);
  glb_kernel<<<1, 128, 0, stream>>>(colsum, glb_W, glb_b, g, 1.0f / (float)N);

  const int egrid = (E + 95) / 96;
  const int ngrid = (N + 63) / 64;
  for (int step = 0; step < 2; ++step) {
    const float* hptr = (step == 0) ? x : out;
    hipMemsetAsync(agg, 0, (size_t)N * DD * sizeof(float), stream);
    edge_mfma_kernel<<<egrid, 256, 0, stream>>>(hptr, src, dst, W1F, W2F,
                                                msg_b1, att_b1, msg_b2, att_W2, att_b2, agg, E);
    node_mfma_kernel<<<ngrid, 256, 0, stream>>>(hptr, agg, U1hiT, U1loT, U2hiT, U2loT,
                                                upd_b1, upd_b2, g, out, N);
  }
}